// Round 3
// baseline (273.778 us; speedup 1.0000x reference)
//
#include <hip/hip_runtime.h>
#include <stdint.h>

typedef int v4i __attribute__((ext_vector_type(4)));

#define GLD_LDS16(gp, lp)                                                              \
  __builtin_amdgcn_global_load_lds((const __attribute__((address_space(1))) void*)(gp), \
                                   (__attribute__((address_space(3))) void*)(lp), 16, 0, 0)

// Inline-asm LDS read: invisible to SIInsertWaitcnts' LDS-DMA alias model, so
// the compiler cannot insert vmcnt(0) drains before it (rule #18 discipline:
// manual lgkmcnt(0) + sched_barrier(0) before the consuming MFMAs).
__device__ __forceinline__ v4i lds_read_b128(uint32_t off) {
  v4i r;
  asm volatile("ds_read_b128 %0, %1" : "=v"(r) : "v"(off));
  return r;
}

#define LGKM_FENCE()                                   \
  do {                                                 \
    asm volatile("s_waitcnt lgkmcnt(0)" ::: "memory"); \
    __builtin_amdgcn_sched_barrier(0);                 \
  } while (0)

// ---------------------------------------------------------------------------
__device__ __forceinline__ void fwht16(float v[16]) {
#pragma unroll
  for (int h = 1; h < 16; h <<= 1) {
#pragma unroll
    for (int i = 0; i < 16; ++i) {
      if (!(i & h)) {
        float a = v[i], b = v[i | h];
        v[i] = a + b;
        v[i | h] = a - b;
      }
    }
  }
}

__global__ __launch_bounds__(256) void fwht_quant_kernel(const float* __restrict__ X,
                                                         int8_t* __restrict__ Q,
                                                         float* __restrict__ S) {
  const int row = blockIdx.x;
  const int t = threadIdx.x;
  __shared__ float lds[4224];
  __shared__ float wred[4];

  const float* xr = X + (size_t)row * 4096;
  float v[16];
  {
    const float4* p = reinterpret_cast<const float4*>(xr) + t * 4;
    float4 a = p[0], b = p[1], c = p[2], d = p[3];
    v[0] = a.x; v[1] = a.y; v[2] = a.z; v[3] = a.w;
    v[4] = b.x; v[5] = b.y; v[6] = b.z; v[7] = b.w;
    v[8] = c.x; v[9] = c.y; v[10] = c.z; v[11] = c.w;
    v[12] = d.x; v[13] = d.y; v[14] = d.z; v[15] = d.w;
  }
  fwht16(v);
#pragma unroll
  for (int e = 0; e < 16; ++e) {
    int idx = t * 16 + e;
    lds[idx + (idx >> 5)] = v[e];
  }
  __syncthreads();
#pragma unroll
  for (int e = 0; e < 16; ++e) {
    int idx = ((t >> 4) << 8) + (e << 4) + (t & 15);
    v[e] = lds[idx + (idx >> 5)];
  }
  fwht16(v);
#pragma unroll
  for (int e = 0; e < 16; ++e) {
    int idx = ((t >> 4) << 8) + (e << 4) + (t & 15);
    lds[idx + (idx >> 5)] = v[e];
  }
  __syncthreads();
#pragma unroll
  for (int e = 0; e < 16; ++e) {
    int idx = (e << 8) + t;
    v[e] = lds[idx + (idx >> 5)];
  }
  fwht16(v);

  float m = 0.f;
#pragma unroll
  for (int e = 0; e < 16; ++e) {
    v[e] *= 0.015625f;
    m = fmaxf(m, fabsf(v[e]));
  }
#pragma unroll
  for (int off = 32; off > 0; off >>= 1) m = fmaxf(m, __shfl_xor(m, off));
  if ((t & 63) == 0) wred[t >> 6] = m;
  __syncthreads();
  m = fmaxf(fmaxf(wred[0], wred[1]), fmaxf(wred[2], wred[3]));
  const float s = fmaxf(m * (1.0f / 127.0f), 1e-8f);
  if (t == 0) S[row] = s;
  int8_t* qr = Q + (size_t)row * 4096;
#pragma unroll
  for (int e = 0; e < 16; ++e) {
    float q = rintf(v[e] / s);
    q = fminf(fmaxf(q, -127.f), 127.f);
    qr[(e << 8) + t] = (int8_t)(int)q;
  }
}

// ---------------------------------------------------------------------------
__global__ __launch_bounds__(256) void lora_t_partial_kernel(const float* __restrict__ X,
                                                             const float* __restrict__ A,
                                                             float* __restrict__ tpart) {
  __shared__ float As[16][512];
  const int t = threadIdx.x;
  const int kc = blockIdx.y;
  const int row = blockIdx.x * 256 + t;
  for (int i = t; i < 2048; i += 256) {
    int r = i >> 7;
    int c4 = i & 127;
    reinterpret_cast<float4*>(&As[r][0])[c4] =
        reinterpret_cast<const float4*>(A + (size_t)r * 4096 + kc * 512)[c4];
  }
  __syncthreads();
  float acc[16];
#pragma unroll
  for (int r = 0; r < 16; ++r) acc[r] = 0.f;
  const float* xr = X + (size_t)row * 4096 + kc * 512;
  for (int k = 0; k < 512; k += 4) {
    float4 xv = *reinterpret_cast<const float4*>(xr + k);
#pragma unroll
    for (int r = 0; r < 16; ++r) {
      float4 av = *reinterpret_cast<const float4*>(&As[r][k]);
      acc[r] += xv.x * av.x + xv.y * av.y + xv.z * av.z + xv.w * av.w;
    }
  }
  float* tp = tpart + ((size_t)kc * 8192 + row) * 16;
#pragma unroll
  for (int r = 0; r < 16; ++r) tp[r] = acc[r];
}

__global__ __launch_bounds__(256) void lora_t_reduce_kernel(const float* __restrict__ tpart,
                                                            float* __restrict__ tmat) {
  int i = blockIdx.x * 256 + threadIdx.x;
  float s = 0.f;
#pragma unroll
  for (int kc = 0; kc < 8; ++kc) s += tpart[(size_t)kc * 131072 + i];
  tmat[i] = s;
}

// ---------------------------------------------------------------------------
// 256x256 8-phase i8 GEMM. BK=128B, 32 K-tiles, 8 waves (2M x 4N).
// Fragment loads are inline-asm ds_read_b128 (bypass LDS-DMA alias drains);
// rule-18 fence (lgkmcnt(0)+sched_barrier) before each MFMA cluster.
__global__ __launch_bounds__(512, 2) void gemm_i8_kernel(
    const int8_t* __restrict__ Aq, const int8_t* __restrict__ Bq,
    const float* __restrict__ Sx, const float* __restrict__ Sw,
    const float* __restrict__ Tm, const float* __restrict__ LB,
    float* __restrict__ out) {
  __shared__ __align__(16) char smem[131072];

  const int tid = threadIdx.x;
  const int lane = tid & 63;
  const int w = tid >> 6;      // 0..7
  const int wm = w >> 2;       // 0..1
  const int wn = w & 3;        // 0..3

  int bid = (int)blockIdx.x;
  bid = (bid & 7) * 64 + (bid >> 3);  // bijective XCD swizzle (512 % 8 == 0)
  const int bm = bid >> 4;            // 0..31
  const int bn = bid & 15;            // 0..15

  const int8_t* Ag = Aq + (size_t)bm * 256 * 4096;
  const int8_t* Bg = Bq + (size_t)bn * 256 * 4096;

  const uint32_t sbase = (uint32_t)(uintptr_t)(void*)smem;  // LDS segment offset

  // ---- staging addresses (per-lane pre-swizzled global source) ----
  const int L0 = w * 1024 + lane * 16;
  const int rS0 = L0 >> 6;
  const int rS1 = rS0 + 128;
  const int cS0 = (((lane & 3) ^ ((rS0 >> 1) & 3)) << 4);

#define STAGE(gbase, ldsOff, kByte)                                                      \
  do {                                                                                   \
    GLD_LDS16((gbase) + (size_t)rS0 * 4096 + (kByte) + cS0, smem + (ldsOff) + w * 1024); \
    GLD_LDS16((gbase) + (size_t)rS1 * 4096 + (kByte) + cS0,                              \
              smem + (ldsOff) + 8192 + w * 1024);                                        \
  } while (0)

  // ---- fragment LDS offsets ----
  int aoff[8], boff[4];
  const int cc = lane >> 4;
#pragma unroll
  for (int mi = 0; mi < 8; ++mi) {
    int r = wm * 128 + mi * 16 + (lane & 15);
    aoff[mi] = r * 64 + ((cc ^ ((r >> 1) & 3)) << 4);
  }
#pragma unroll
  for (int ni = 0; ni < 4; ++ni) {
    int r = wn * 64 + ni * 16 + (lane & 15);
    boff[ni] = r * 64 + ((cc ^ ((r >> 1) & 3)) << 4);
  }

  v4i acc[8][4];
#pragma unroll
  for (int i = 0; i < 8; ++i)
#pragma unroll
    for (int n = 0; n < 4; ++n) {
      v4i z = {0, 0, 0, 0};
      acc[i][n] = z;
    }

  // ---- prologue ----
  STAGE(Ag, 0, 0);
  STAGE(Bg, 32768, 0);
  STAGE(Ag, 16384, 64);
  STAGE(Bg, 49152, 64);
  asm volatile("s_waitcnt vmcnt(4)" ::: "memory");  // A-k0,B-k0 landed
  __builtin_amdgcn_s_barrier();
  __builtin_amdgcn_sched_barrier(0);

#define MFMA_CLUSTER(MH)                                                                  \
  do {                                                                                    \
    __builtin_amdgcn_s_setprio(1);                                                        \
    _Pragma("unroll") for (int i = 0; i < 4; ++i) _Pragma("unroll") for (int n = 0;       \
                                                                        n < 4; ++n)       \
        acc[(MH)*4 + i][n] =                                                              \
        __builtin_amdgcn_mfma_i32_16x16x64_i8(af[i], bf[n], acc[(MH)*4 + i][n], 0, 0, 0); \
    __builtin_amdgcn_s_setprio(0);                                                        \
  } while (0)

#pragma unroll 1
  for (int t = 0; t < 32; ++t) {
    const uint32_t Ab = sbase + (t & 1) * 65536;
    const uint32_t Bb = Ab + 32768;
    const int nx = ((t & 1) ^ 1) * 65536;
    const bool pf = (t + 1) < 32;
    const int kB = (t + 1) << 7;
    v4i af[4], bf[4];

    // ---- phase 1: (mh0, kk0); stage A-k0(t+1)
    if (pf) STAGE(Ag, nx + 0, kB);
#pragma unroll
    for (int i = 0; i < 4; ++i) af[i] = lds_read_b128(Ab + aoff[i]);
#pragma unroll
    for (int n = 0; n < 4; ++n) bf[n] = lds_read_b128(Bb + boff[n]);
    __builtin_amdgcn_s_barrier();
    LGKM_FENCE();
    MFMA_CLUSTER(0);
    __builtin_amdgcn_s_barrier();

    // ---- phase 2: (mh1, kk0); stage B-k0(t+1)
    if (pf) STAGE(Bg, nx + 32768, kB);
#pragma unroll
    for (int i = 0; i < 4; ++i) af[i] = lds_read_b128(Ab + aoff[4 + i]);
    __builtin_amdgcn_s_barrier();
    LGKM_FENCE();
    MFMA_CLUSTER(1);
    if (pf)
      asm volatile("s_waitcnt vmcnt(4)" ::: "memory");  // A-k1(t),B-k1(t) landed
    else
      asm volatile("s_waitcnt vmcnt(0)" ::: "memory");
    __builtin_amdgcn_s_barrier();
    __builtin_amdgcn_sched_barrier(0);

    // ---- phase 3: (mh0, kk1); stage A-k1(t+1)
    if (pf) STAGE(Ag, nx + 16384, kB + 64);
#pragma unroll
    for (int i = 0; i < 4; ++i) af[i] = lds_read_b128(Ab + 16384 + aoff[i]);
#pragma unroll
    for (int n = 0; n < 4; ++n) bf[n] = lds_read_b128(Bb + 16384 + boff[n]);
    __builtin_amdgcn_s_barrier();
    LGKM_FENCE();
    MFMA_CLUSTER(0);
    __builtin_amdgcn_s_barrier();

    // ---- phase 4: (mh1, kk1); stage B-k1(t+1)
    if (pf) STAGE(Bg, nx + 49152, kB + 64);
#pragma unroll
    for (int i = 0; i < 4; ++i) af[i] = lds_read_b128(Ab + 16384 + aoff[4 + i]);
    __builtin_amdgcn_s_barrier();
    LGKM_FENCE();
    MFMA_CLUSTER(1);
    if (pf) asm volatile("s_waitcnt vmcnt(4)" ::: "memory");  // A-k0,B-k0(t+1) landed
    __builtin_amdgcn_s_barrier();
    __builtin_amdgcn_sched_barrier(0);
  }

  // ---- epilogue: scales + fused LoRA ----
  __syncthreads();
  float* tl = (float*)smem;              // [256][17]
  float* bl = (float*)(smem + 17408);    // [256][17]
  for (int i = tid; i < 1024; i += 512) {
    int r = i >> 2, q4 = (i & 3) * 4;
    float4 tv = *reinterpret_cast<const float4*>(Tm + (size_t)(bm * 256 + r) * 16 + q4);
    tl[r * 17 + q4 + 0] = tv.x;
    tl[r * 17 + q4 + 1] = tv.y;
    tl[r * 17 + q4 + 2] = tv.z;
    tl[r * 17 + q4 + 3] = tv.w;
    float4 bv = *reinterpret_cast<const float4*>(LB + (size_t)(bn * 256 + r) * 16 + q4);
    bl[r * 17 + q4 + 0] = bv.x;
    bl[r * 17 + q4 + 1] = bv.y;
    bl[r * 17 + q4 + 2] = bv.z;
    bl[r * 17 + q4 + 3] = bv.w;
  }
  __syncthreads();

  float blv[4][16], swv[4];
#pragma unroll
  for (int ni = 0; ni < 4; ++ni) {
    int cl = wn * 64 + ni * 16 + (lane & 15);
    swv[ni] = Sw[bn * 256 + cl];
#pragma unroll
    for (int q = 0; q < 16; ++q) blv[ni][q] = bl[cl * 17 + q];
  }
#pragma unroll
  for (int mi = 0; mi < 8; ++mi) {
#pragma unroll
    for (int rr = 0; rr < 4; ++rr) {
      int rl = wm * 128 + mi * 16 + (lane >> 4) * 4 + rr;  // C/D: row=(l>>4)*4+reg
      float sxv = Sx[bm * 256 + rl];
      float tv[16];
#pragma unroll
      for (int q = 0; q < 16; ++q) tv[q] = tl[rl * 17 + q];
      float* orow = out + (size_t)(bm * 256 + rl) * 4096 + bn * 256;
#pragma unroll
      for (int ni = 0; ni < 4; ++ni) {
        float dot = 0.f;
#pragma unroll
        for (int q = 0; q < 16; ++q) dot = fmaf(tv[q], blv[ni][q], dot);
        int cl = wn * 64 + ni * 16 + (lane & 15);  // C/D: col = l&15
        orow[cl] = sxv * swv[ni] * (float)acc[mi][ni][rr] + 2.0f * dot;
      }
    }
  }
}

// ---------------------------------------------------------------------------
extern "C" void kernel_launch(void* const* d_in, const int* in_sizes, int n_in,
                              void* d_out, int out_size, void* d_ws, size_t ws_size,
                              hipStream_t stream) {
  const float* x = (const float*)d_in[0];     // 8192 x 4096
  const float* wgt = (const float*)d_in[1];   // 4096 x 4096
  const float* lA = (const float*)d_in[2];    // 16 x 4096
  const float* lB = (const float*)d_in[3];    // 4096 x 16
  float* out = (float*)d_out;                 // 8192 x 4096

  char* ws = (char*)d_ws;
  int8_t* qx = (int8_t*)ws;
  int8_t* qw = (int8_t*)(ws + 33554432);
  float* sx = (float*)(ws + 50331648);
  float* sw = (float*)(ws + 50364416);
  float* tmat = (float*)(ws + 50380800);
  float* tpart = (float*)(ws + 50905088);

  fwht_quant_kernel<<<8192, 256, 0, stream>>>(x, qx, sx);
  fwht_quant_kernel<<<4096, 256, 0, stream>>>(wgt, qw, sw);
  lora_t_partial_kernel<<<dim3(32, 8), 256, 0, stream>>>(x, lA, tpart);
  lora_t_reduce_kernel<<<512, 256, 0, stream>>>(tpart, tmat);
  gemm_i8_kernel<<<512, 512, 0, stream>>>(qx, qw, sx, sw, tmat, lB, out);
}

// Round 4
// 265.750 us; speedup vs baseline: 1.0302x; 1.0302x over previous
//
#include <hip/hip_runtime.h>
#include <stdint.h>

typedef int v4i __attribute__((ext_vector_type(4)));

#define GLD_LDS16(gp, lp)                                                              \
  __builtin_amdgcn_global_load_lds((const __attribute__((address_space(1))) void*)(gp), \
                                   (__attribute__((address_space(3))) void*)(lp), 16, 0, 0)

__device__ __forceinline__ v4i lds_read_b128(uint32_t off) {
  v4i r;
  asm volatile("ds_read_b128 %0, %1" : "=v"(r) : "v"(off));
  return r;
}

#define LGKM_FENCE()                                   \
  do {                                                 \
    asm volatile("s_waitcnt lgkmcnt(0)" ::: "memory"); \
    __builtin_amdgcn_sched_barrier(0);                 \
  } while (0)

// ---------------------------------------------------------------------------
__device__ __forceinline__ void fwht16(float v[16]) {
#pragma unroll
  for (int h = 1; h < 16; h <<= 1) {
#pragma unroll
    for (int i = 0; i < 16; ++i) {
      if (!(i & h)) {
        float a = v[i], b = v[i | h];
        v[i] = a + b;
        v[i | h] = a - b;
      }
    }
  }
}

__global__ __launch_bounds__(256) void fwht_quant_kernel(const float* __restrict__ X,
                                                         int8_t* __restrict__ Q,
                                                         float* __restrict__ S) {
  const int row = blockIdx.x;
  const int t = threadIdx.x;
  __shared__ float lds[4224];
  __shared__ float wred[4];

  const float* xr = X + (size_t)row * 4096;
  float v[16];
  {
    const float4* p = reinterpret_cast<const float4*>(xr) + t * 4;
    float4 a = p[0], b = p[1], c = p[2], d = p[3];
    v[0] = a.x; v[1] = a.y; v[2] = a.z; v[3] = a.w;
    v[4] = b.x; v[5] = b.y; v[6] = b.z; v[7] = b.w;
    v[8] = c.x; v[9] = c.y; v[10] = c.z; v[11] = c.w;
    v[12] = d.x; v[13] = d.y; v[14] = d.z; v[15] = d.w;
  }
  fwht16(v);
#pragma unroll
  for (int e = 0; e < 16; ++e) {
    int idx = t * 16 + e;
    lds[idx + (idx >> 5)] = v[e];
  }
  __syncthreads();
#pragma unroll
  for (int e = 0; e < 16; ++e) {
    int idx = ((t >> 4) << 8) + (e << 4) + (t & 15);
    v[e] = lds[idx + (idx >> 5)];
  }
  fwht16(v);
#pragma unroll
  for (int e = 0; e < 16; ++e) {
    int idx = ((t >> 4) << 8) + (e << 4) + (t & 15);
    lds[idx + (idx >> 5)] = v[e];
  }
  __syncthreads();
#pragma unroll
  for (int e = 0; e < 16; ++e) {
    int idx = (e << 8) + t;
    v[e] = lds[idx + (idx >> 5)];
  }
  fwht16(v);

  float m = 0.f;
#pragma unroll
  for (int e = 0; e < 16; ++e) {
    v[e] *= 0.015625f;
    m = fmaxf(m, fabsf(v[e]));
  }
#pragma unroll
  for (int off = 32; off > 0; off >>= 1) m = fmaxf(m, __shfl_xor(m, off));
  if ((t & 63) == 0) wred[t >> 6] = m;
  __syncthreads();
  m = fmaxf(fmaxf(wred[0], wred[1]), fmaxf(wred[2], wred[3]));
  const float s = fmaxf(m * (1.0f / 127.0f), 1e-8f);
  if (t == 0) S[row] = s;
  int8_t* qr = Q + (size_t)row * 4096;
#pragma unroll
  for (int e = 0; e < 16; ++e) {
    float q = rintf(v[e] / s);
    q = fminf(fmaxf(q, -127.f), 127.f);
    qr[(e << 8) + t] = (int8_t)(int)q;
  }
}

// ---------------------------------------------------------------------------
__global__ __launch_bounds__(256) void lora_t_partial_kernel(const float* __restrict__ X,
                                                             const float* __restrict__ A,
                                                             float* __restrict__ tpart) {
  __shared__ float As[16][512];
  const int t = threadIdx.x;
  const int kc = blockIdx.y;
  const int row = blockIdx.x * 256 + t;
  for (int i = t; i < 2048; i += 256) {
    int r = i >> 7;
    int c4 = i & 127;
    reinterpret_cast<float4*>(&As[r][0])[c4] =
        reinterpret_cast<const float4*>(A + (size_t)r * 4096 + kc * 512)[c4];
  }
  __syncthreads();
  float acc[16];
#pragma unroll
  for (int r = 0; r < 16; ++r) acc[r] = 0.f;
  const float* xr = X + (size_t)row * 4096 + kc * 512;
  for (int k = 0; k < 512; k += 4) {
    float4 xv = *reinterpret_cast<const float4*>(xr + k);
#pragma unroll
    for (int r = 0; r < 16; ++r) {
      float4 av = *reinterpret_cast<const float4*>(&As[r][k]);
      acc[r] += xv.x * av.x + xv.y * av.y + xv.z * av.z + xv.w * av.w;
    }
  }
  float* tp = tpart + ((size_t)kc * 8192 + row) * 16;
#pragma unroll
  for (int r = 0; r < 16; ++r) tp[r] = acc[r];
}

__global__ __launch_bounds__(256) void lora_t_reduce_kernel(const float* __restrict__ tpart,
                                                            float* __restrict__ tmat) {
  int i = blockIdx.x * 256 + threadIdx.x;
  float s = 0.f;
#pragma unroll
  for (int kc = 0; kc < 8; ++kc) s += tpart[(size_t)kc * 131072 + i];
  tmat[i] = s;
}

// ---------------------------------------------------------------------------
// 256x256 i8 GEMM, free-running 1-barrier-per-K-tile schedule.
// LDS: 2 bufs x (A[256r][128B] + B[256r][128B]) = 128 KB.
// Swizzle: 16B chunk (0..7) ^= (row&7), applied both-sides (pre-swizzled
// global source for the DMA stage; swizzled ds_read addrs). Full-128B rows
// -> each L2 line fetched once.
// Per tile: {stage 8 gld_lds (next tile) ; 4x(ds_read, lgkm0, 16 MFMA) ;
// vmcnt(0) ; s_barrier}. Loads stay in flight across the whole tile body,
// so the vmcnt(0) waits on ~2600-cycle-old loads (nearly free). No intra-tile
// cross-wave hazards exist (reads buf(t), DMA writes buf(t+1)).
__global__ __launch_bounds__(512, 2) void gemm_i8_kernel(
    const int8_t* __restrict__ Aq, const int8_t* __restrict__ Bq,
    const float* __restrict__ Sx, const float* __restrict__ Sw,
    const float* __restrict__ Tm, const float* __restrict__ LB,
    float* __restrict__ out) {
  __shared__ __align__(16) char smem[131072];

  const int tid = threadIdx.x;
  const int lane = tid & 63;
  const int w = tid >> 6;      // 0..7
  const int wm = w >> 2;       // 0..1
  const int wn = w & 3;        // 0..3

  int bid = (int)blockIdx.x;
  bid = (bid & 7) * 64 + (bid >> 3);  // bijective XCD swizzle (512 % 8 == 0)
  const int bm = bid >> 4;            // 0..31
  const int bn = bid & 15;            // 0..15

  const int8_t* Ag = Aq + (size_t)bm * 256 * 4096;
  const int8_t* Bg = Bq + (size_t)bn * 256 * 4096;

  const uint32_t sbase = (uint32_t)(uintptr_t)(void*)smem;

  // ---- staging geometry: 4 loads per wave per operand-tile (32 KB) ----
  // linear LDS offset = opBase + w*4096 + j*1024 + lane*16
  // row = w*32 + j*8 + (lane>>3); dest chunk = lane&7;
  // source chunk = (lane&7) ^ (row&7), row&7 == lane>>3.
  const int row0 = w * 32 + (lane >> 3);
  const int srcOff = (((lane & 7) ^ (lane >> 3)) << 4);

#define STAGE_OP(gbase, ldsOpBase, tByte)                                        \
  do {                                                                           \
    _Pragma("unroll") for (int j = 0; j < 4; ++j)                                \
        GLD_LDS16((gbase) + (size_t)(row0 + j * 8) * 4096 + (tByte) + srcOff,    \
                  smem + (ldsOpBase) + w * 4096 + j * 1024);                     \
  } while (0)

  // ---- fragment LDS offsets (kk=0; kk=1 is ^64) ----
  // A frag row r = wm*128+mi*16+(lane&15); chunk = (lane>>4) ^ (r&7), r&7=lane&7
  int aoff[8], boff[4];
  const int fch = (((lane >> 4) ^ (lane & 7)) << 4);
#pragma unroll
  for (int mi = 0; mi < 8; ++mi) {
    int r = wm * 128 + mi * 16 + (lane & 15);
    aoff[mi] = r * 128 + fch;
  }
#pragma unroll
  for (int ni = 0; ni < 4; ++ni) {
    int r = wn * 64 + ni * 16 + (lane & 15);
    boff[ni] = 32768 + r * 128 + fch;
  }

  v4i acc[8][4];
#pragma unroll
  for (int i = 0; i < 8; ++i)
#pragma unroll
    for (int n = 0; n < 4; ++n) {
      v4i z = {0, 0, 0, 0};
      acc[i][n] = z;
    }

  // ---- prologue: stage tile 0 into buf0 ----
  STAGE_OP(Ag, 0, 0);
  STAGE_OP(Bg, 32768, 0);
  asm volatile("s_waitcnt vmcnt(0)" ::: "memory");
  __builtin_amdgcn_s_barrier();
  __builtin_amdgcn_sched_barrier(0);

#define MFMA16(MH)                                                                        \
  do {                                                                                    \
    __builtin_amdgcn_s_setprio(1);                                                        \
    _Pragma("unroll") for (int i = 0; i < 4; ++i) _Pragma("unroll") for (int n = 0;       \
                                                                        n < 4; ++n)       \
        acc[(MH)*4 + i][n] =                                                              \
        __builtin_amdgcn_mfma_i32_16x16x64_i8(af[i], bf[n], acc[(MH)*4 + i][n], 0, 0, 0); \
    __builtin_amdgcn_s_setprio(0);                                                        \
  } while (0)

#pragma unroll 1
  for (int t = 0; t < 32; ++t) {
    const uint32_t Ab = sbase + (t & 1) * 65536;
    const int nx = ((t & 1) ^ 1) * 65536;
    const bool pf = (t + 1) < 32;
    const int tB = (t + 1) << 7;
    v4i af[4], bf[4];

    // stage next tile (8 loads, in flight across the whole tile body)
    if (pf) {
      STAGE_OP(Ag, nx, tB);
      STAGE_OP(Bg, nx + 32768, tB);
    }

    // ---- kk0, mi 0-3 ----
#pragma unroll
    for (int n = 0; n < 4; ++n) bf[n] = lds_read_b128(Ab + boff[n]);
#pragma unroll
    for (int i = 0; i < 4; ++i) af[i] = lds_read_b128(Ab + aoff[i]);
    LGKM_FENCE();
    MFMA16(0);
    // ---- kk0, mi 4-7 ----
#pragma unroll
    for (int i = 0; i < 4; ++i) af[i] = lds_read_b128(Ab + aoff[4 + i]);
    LGKM_FENCE();
    MFMA16(1);
    // ---- kk1, mi 0-3 ----
#pragma unroll
    for (int n = 0; n < 4; ++n) bf[n] = lds_read_b128(Ab + (boff[n] ^ 64));
#pragma unroll
    for (int i = 0; i < 4; ++i) af[i] = lds_read_b128(Ab + (aoff[i] ^ 64));
    LGKM_FENCE();
    MFMA16(0);
    // ---- kk1, mi 4-7 ----
#pragma unroll
    for (int i = 0; i < 4; ++i) af[i] = lds_read_b128(Ab + (aoff[4 + i] ^ 64));
    LGKM_FENCE();
    MFMA16(1);

    // ---- tile boundary: publish buf(t+1), release buf(t) ----
    asm volatile("s_waitcnt vmcnt(0)" ::: "memory");
    __builtin_amdgcn_s_barrier();
    __builtin_amdgcn_sched_barrier(0);
  }

  // ---- epilogue: scales + fused LoRA ----
  __syncthreads();
  float* tl = (float*)smem;              // [256][17]
  float* bl = (float*)(smem + 17408);    // [256][17]
  for (int i = tid; i < 1024; i += 512) {
    int r = i >> 2, q4 = (i & 3) * 4;
    float4 tv = *reinterpret_cast<const float4*>(Tm + (size_t)(bm * 256 + r) * 16 + q4);
    tl[r * 17 + q4 + 0] = tv.x;
    tl[r * 17 + q4 + 1] = tv.y;
    tl[r * 17 + q4 + 2] = tv.z;
    tl[r * 17 + q4 + 3] = tv.w;
    float4 bv = *reinterpret_cast<const float4*>(LB + (size_t)(bn * 256 + r) * 16 + q4);
    bl[r * 17 + q4 + 0] = bv.x;
    bl[r * 17 + q4 + 1] = bv.y;
    bl[r * 17 + q4 + 2] = bv.z;
    bl[r * 17 + q4 + 3] = bv.w;
  }
  __syncthreads();

  float blv[4][16], swv[4];
#pragma unroll
  for (int ni = 0; ni < 4; ++ni) {
    int cl = wn * 64 + ni * 16 + (lane & 15);
    swv[ni] = Sw[bn * 256 + cl];
#pragma unroll
    for (int q = 0; q < 16; ++q) blv[ni][q] = bl[cl * 17 + q];
  }
#pragma unroll
  for (int mi = 0; mi < 8; ++mi) {
#pragma unroll
    for (int rr = 0; rr < 4; ++rr) {
      int rl = wm * 128 + mi * 16 + (lane >> 4) * 4 + rr;  // C/D: row=(l>>4)*4+reg
      float sxv = Sx[bm * 256 + rl];
      float tv[16];
#pragma unroll
      for (int q = 0; q < 16; ++q) tv[q] = tl[rl * 17 + q];
      float* orow = out + (size_t)(bm * 256 + rl) * 4096 + bn * 256;
#pragma unroll
      for (int ni = 0; ni < 4; ++ni) {
        float dot = 0.f;
#pragma unroll
        for (int q = 0; q < 16; ++q) dot = fmaf(tv[q], blv[ni][q], dot);
        int cl = wn * 64 + ni * 16 + (lane & 15);  // C/D: col = l&15
        orow[cl] = sxv * swv[ni] * (float)acc[mi][ni][rr] + 2.0f * dot;
      }
    }
  }
}

// ---------------------------------------------------------------------------
extern "C" void kernel_launch(void* const* d_in, const int* in_sizes, int n_in,
                              void* d_out, int out_size, void* d_ws, size_t ws_size,
                              hipStream_t stream) {
  const float* x = (const float*)d_in[0];     // 8192 x 4096
  const float* wgt = (const float*)d_in[1];   // 4096 x 4096
  const float* lA = (const float*)d_in[2];    // 16 x 4096
  const float* lB = (const float*)d_in[3];    // 4096 x 16
  float* out = (float*)d_out;                 // 8192 x 4096

  char* ws = (char*)d_ws;
  int8_t* qx = (int8_t*)ws;
  int8_t* qw = (int8_t*)(ws + 33554432);
  float* sx = (float*)(ws + 50331648);
  float* sw = (float*)(ws + 50364416);
  float* tmat = (float*)(ws + 50380800);
  float* tpart = (float*)(ws + 50905088);

  fwht_quant_kernel<<<8192, 256, 0, stream>>>(x, qx, sx);
  fwht_quant_kernel<<<4096, 256, 0, stream>>>(wgt, qw, sw);
  lora_t_partial_kernel<<<dim3(32, 8), 256, 0, stream>>>(x, lA, tpart);
  lora_t_reduce_kernel<<<512, 256, 0, stream>>>(tpart, tmat);
  gemm_i8_kernel<<<512, 512, 0, stream>>>(qx, qw, sx, sw, tmat, lB, out);
}